// Round 1
// baseline (124.461 us; speedup 1.0000x reference)
//
#include <hip/hip_runtime.h>
#include <stdint.h>

// HashGrid encoding — but the reference's xf = (xs - xs) == 0 bug collapses
// trilinear interpolation to a single gather at the all-floor corner:
//   out[i] = embedding[ (i0*1 ^ i1*2654435761 ^ i2*805459861) & 0x7FFFF ]
// Pure memory-bound gather: ~24MB x read + ~16MB table + 64MB out write.

#define N_POINTS_C   2097152
#define HASH_MASK    0x7FFFFu     // HASHMAP_SIZE = 2^19

__global__ __launch_bounds__(256) void _HashGridMLP_33706903339712_kernel(
    const float* __restrict__ x,
    const float* __restrict__ emb,
    float* __restrict__ out,
    int n)
{
    int i = blockIdx.x * blockDim.x + threadIdx.x;
    if (i >= n) return;

    // Stride-3 scalar loads: the wave's 64 lanes cover 768 contiguous bytes,
    // each cache line fetched once (L1 absorbs the 3x revisit).
    float x0 = x[3 * i + 0];
    float x1 = x[3 * i + 1];
    float x2 = x[3 * i + 2];

    // xs = x * 128.0f (exact pow2 scale); astype(int32) truncates toward zero,
    // identical to C++ (int32_t) cast. x in [0,1) -> idx in [0,127].
    uint32_t i0 = (uint32_t)(int32_t)(x0 * 128.0f);
    uint32_t i1 = (uint32_t)(int32_t)(x1 * 128.0f);
    uint32_t i2 = (uint32_t)(int32_t)(x2 * 128.0f);

    // uint32 multiply wraps mod 2^32, matching jnp uint32 semantics.
    uint32_t h = i0 ^ (i1 * 2654435761u) ^ (i2 * 805459861u);
    h &= HASH_MASK;

    // 32B gather from the table (random; L2/L3-resident) + 32B coalesced store.
    const float4* e = reinterpret_cast<const float4*>(emb) + 2 * (size_t)h;
    float4 a = e[0];
    float4 b = e[1];
    float4* o = reinterpret_cast<float4*>(out) + 2 * (size_t)i;
    o[0] = a;
    o[1] = b;
}

extern "C" void kernel_launch(void* const* d_in, const int* in_sizes, int n_in,
                              void* d_out, int out_size, void* d_ws, size_t ws_size,
                              hipStream_t stream) {
    const float* x   = (const float*)d_in[0];   // [N, 3] f32
    const float* emb = (const float*)d_in[1];   // [524288, 8] f32
    float* out = (float*)d_out;                 // [N, 8] f32

    int n = in_sizes[0] / 3;                    // N_POINTS
    int block = 256;
    int grid = (n + block - 1) / block;
    _HashGridMLP_33706903339712_kernel<<<grid, block, 0, stream>>>(x, emb, out, n);
}